// Round 5
// baseline (335.422 us; speedup 1.0000x reference)
//
#include <hip/hip_runtime.h>

// GraphConv B=256,N=512,D=6,F=128,MAX_DEG=6.
// R10 post-mortem: dur INVARIANT (67us) across occupancy 20->40%, conflicts
// -40%, phase-B barriers 24->0. Empirical law over 5 rounds: dur = hbm_bytes
// / BW, BW tracks INDEPENDENT blocks/CU (1blk:1.5 TB/s, 2blk:1.6, 4blk:2.3)
// -> request-concurrency-bound: one barrier-synced block/CU gives bursty
// memory traffic (~25% duty cycle). R11: quarter-molecule fused blocks.
// Block=(mol,quarter): own 128 rows' summed (34.8KB) + full-mol 8-float
// abuf slice (16KB) => ~52KB LDS -> 3 INDEPENDENT blocks/CU. Edges read
// once/row; atoms staged x4/mol from L2/L3 (HBM-flat). Phase B per-quarter
// flattened MFMA items, B-frags direct from global Wt (L2-hot).

typedef short bf16x8 __attribute__((ext_vector_type(8)));
typedef float f32x4  __attribute__((ext_vector_type(4)));
typedef unsigned short ushort_t;
typedef unsigned int uint_t;

constexpr int Nn = 512;
constexpr int Ff = 128;

// ws: Wt bf16 [6][128][128] ([d][n][k])
constexpr size_t WS_NEEDED = 196608;

__device__ inline ushort_t f2bf(float f) {              // round-to-nearest-even
    uint_t u = __float_as_uint(f);
    return (ushort_t)((u + 0x7FFFu + ((u >> 16) & 1u)) >> 16);
}

__device__ inline bool detect_is64(const int* edges32) {
    // int64 edges: odd dwords are sign-extension words in {0,-1}.
    int probe = edges32[2 * (threadIdx.x & 63) + 1];
    return __any(probe > 0) == 0;
}

// ---------------- k0: W fp32 [d][k][n] -> Wt bf16 [d][n][k] ----------------
__global__ __launch_bounds__(1024)
void k0_wt(const float* __restrict__ W, ushort_t* __restrict__ Wt) {
    int L = blockIdx.x * 1024 + threadIdx.x;     // 96 blocks x 1024 = 98304
    int d = L >> 14, rem = L & 16383;
    int n = rem >> 7, k = rem & 127;
    Wt[L] = f2bf(W[(d << 14) + (k << 7) + n]);   // W is 384KB -> L2-resident
}

// ---------------- fused: quarter-molecule per block ----------------
// 1024 blocks = 256 mols x 4 quarters; 256 threads (4 waves).
// LDS ~52KB -> 3 independent blocks/CU (the concurrency lever).
__global__ __launch_bounds__(256)
void k_fused(const float* __restrict__ atoms,
             const int*   __restrict__ edges32,
             const ushort_t* __restrict__ Wt,
             const float* __restrict__ bias,
             float* __restrict__ out) {
    const int tid = threadIdx.x;
    const int mol = blockIdx.x >> 2;
    const int qr  = blockIdx.x & 3;
    const int r0  = qr * 128;                    // own rows [r0, r0+128)
    const bool is64 = detect_is64(edges32);      // convergent

    __shared__ ushort_t summed[128 * 136];       // 34816 B (272B rows, 16B-aligned)
    __shared__ float4   abuf4[Nn * 2];           // 16384 B: full-mol 8-float slice, swizzled
    __shared__ ushort_t rlist[128];              // own rows grouped by degree
    __shared__ int hist[6], base_sh[8];

    // --- prefetch atom slice 0 (floats 0..7 of ALL 512 rows): 4 float4/thread ---
    const float4* gsrc = (const float4*)(atoms + (size_t)mol * (Nn * Ff));
    float4 pf[4];
    #pragma unroll
    for (int it = 0; it < 4; it++) {
        int idx = tid + it * 256;                // row=idx>>1, c=idx&1
        pf[it] = gsrc[(idx >> 1) * 32 + (idx & 1)];
    }

    // --- own row (pair of threads) + its edges; degree ranks ---
    const int pr = tid >> 1, h = tid & 1;        // local row pr in [0,128)
    const int row_g = r0 + pr;                   // row in molecule
    int er[6], deg = 0;
    {
        const size_t eb = (size_t)mol * (Nn * 6) + (size_t)row_g * 6;
        #pragma unroll
        for (int j = 0; j < 6; j++) {
            er[j] = is64 ? edges32[(eb + j) * 2] : edges32[eb + j];
            deg += (er[j] >= 0) ? 1 : 0;
        }
        if (deg > 5) deg = 5;                    // input spec: deg<=5; guard OOB
    }
    if (tid < 6) hist[tid] = 0;
    __syncthreads();
    int rk = 0;
    if (h == 0) rk = atomicAdd(&hist[deg], 1);
    __syncthreads();
    if (tid == 0) {
        int a = 0;
        #pragma unroll
        for (int d = 0; d < 6; d++) { base_sh[d] = a; a += hist[d]; }
    }
    __syncthreads();
    if (h == 0) rlist[base_sh[deg] + rk] = (ushort_t)pr;
    // land slice-0. Swizzle: granule c of row r at [2r + (c ^ (r&1))]
    #pragma unroll
    for (int it = 0; it < 4; it++) {
        int idx = tid + it * 256, r = idx >> 1, c = idx & 1;
        abuf4[2 * r + (c ^ (r & 1))] = pf[it];
    }
    __syncthreads();                             // rlist + abuf ready

    // --- phase A: 16 slices of 8 floats; pair handles 4 floats of own row ---
    for (int s = 0; s < 16; s++) {
        if (s < 15) {                            // issue next-slice loads early
            #pragma unroll
            for (int it = 0; it < 4; it++) {
                int idx = tid + it * 256;
                pf[it] = gsrc[(idx >> 1) * 32 + (s + 1) * 2 + (idx & 1)];
            }
        }
        float4 a = abuf4[2 * row_g + (h ^ (row_g & 1))];       // self
        #pragma unroll
        for (int j = 0; j < 6; j++) {
            int e = er[j];
            if (e >= 0) {
                float4 v = abuf4[2 * e + (h ^ (e & 1))];
                a.x += v.x; a.y += v.y; a.z += v.z; a.w += v.w;
            }
        }
        uint2 o;
        o.x = (uint_t)f2bf(a.x) | ((uint_t)f2bf(a.y) << 16);
        o.y = (uint_t)f2bf(a.z) | ((uint_t)f2bf(a.w) << 16);
        *(uint2*)&summed[pr * 136 + s * 8 + h * 4] = o;
        __syncthreads();                         // all abuf reads done
        if (s < 15) {
            #pragma unroll
            for (int it = 0; it < 4; it++) {
                int idx = tid + it * 256, r = idx >> 1, c = idx & 1;
                abuf4[2 * r + (c ^ (r & 1))] = pf[it];
            }
            __syncthreads();                     // abuf ready for next gather
        }
    }
    // (s=15 ended with barrier: summed complete)

    // --- phase B: flattened barrier-free MFMA items over own 128 rows ---
    const int lane = tid & 63, wid = tid >> 6;   // wid 0..3
    const int kq = lane >> 4, ml = lane & 15;

    int cnts[6], cbase[6], Tp[7];
    {
        int a = 0, b = 0;
        #pragma unroll
        for (int d = 0; d < 6; d++) {
            cnts[d] = hist[d];
            cbase[d] = b; b += cnts[d];
            Tp[d] = a; a += ((cnts[d] + 15) >> 4) * 4;   // items = Td * 4 col-pairs
        }
        Tp[6] = a;
    }
    const int items = Tp[6];

    for (int it = wid; it < items; it += 4) {
        int d = 0;
        #pragma unroll
        for (int dd = 1; dd < 6; dd++) if (it >= Tp[dd]) d = dd;
        const int loc = it - Tp[d];
        const int ti = loc >> 2, ci = loc & 3;   // row-tile, col-pair
        const int cn = cnts[d], cb = cbase[d];

        int lidx = ti * 16 + ml;
        int cl = (lidx < cn) ? lidx : cn - 1;    // clamp; stores masked
        int row = rlist[cb + cl];                // local row
        bf16x8 af[4];                            // A: m=ml, k=kq*8+k0*32
        #pragma unroll
        for (int k0 = 0; k0 < 4; k0++)
            af[k0] = *(const bf16x8*)&summed[row * 136 + kq * 8 + k0 * 32];
        int orw[4];                              // C/D rows: kq*4+reg (local)
        #pragma unroll
        for (int r = 0; r < 4; r++) {
            int li = ti * 16 + kq * 4 + r;
            orw[r] = (li < cn) ? (int)rlist[cb + li] : -1;
        }
        const ushort_t* wg = Wt + (size_t)d * 16384;
        #pragma unroll
        for (int n2 = 0; n2 < 2; n2++) {
            const int nt = ci * 2 + n2;
            bf16x8 bfr[4];                       // B: n=ml, k=kq*8+k0*32 (global, L2-hot)
            #pragma unroll
            for (int k0 = 0; k0 < 4; k0++)
                bfr[k0] = *(const bf16x8*)&wg[(nt * 16 + ml) * 128 + k0 * 32 + kq * 8];
            f32x4 c = {0.f, 0.f, 0.f, 0.f};
            #pragma unroll
            for (int k0 = 0; k0 < 4; k0++)
                c = __builtin_amdgcn_mfma_f32_16x16x32_bf16(af[k0], bfr[k0], c, 0, 0, 0);
            const int col = nt * 16 + ml;
            const float bc = bias[d * Ff + col];
            #pragma unroll
            for (int r = 0; r < 4; r++) {
                if (orw[r] >= 0) {
                    float v = c[r] + bc;
                    out[((size_t)mol * Nn + r0 + orw[r]) * Ff + col] = v > 0.f ? v : 0.f;
                }
            }
        }
    }
}

// ---------------- fallback (round-1 kernel) if ws too small ----------------
__global__ __launch_bounds__(128, 2)
void graphconv_fallback(const float* __restrict__ atoms,
                        const int* __restrict__ edges_raw,
                        const float* __restrict__ W,
                        const float* __restrict__ bias,
                        float* __restrict__ out) {
    const int tid = threadIdx.x;
    const int d = blockIdx.x % 6;
    const int k = blockIdx.x / 6;
    const int a0 = k * 256;
    __shared__ int eds[256 * 6];
    __shared__ int list[256];
    __shared__ int cnt;
    __shared__ float sv[2][Ff];
    bool is64;
    { int v = edges_raw[2 * (tid & 63) + 1]; is64 = (__ballot(v > 0) == 0ull); }
    if (!is64) { for (int i = tid; i < 256 * 6; i += 128) eds[i] = edges_raw[a0 * 6 + i]; }
    else       { for (int i = tid; i < 256 * 6; i += 128) eds[i] = edges_raw[2 * (a0 * 6 + i)]; }
    if (tid == 0) cnt = 0;
    __syncthreads();
    for (int i = tid; i < 256; i += 128) {
        int deg = 0;
        #pragma unroll
        for (int j = 0; j < 6; j++) deg += (eds[i * 6 + j] != -1) ? 1 : 0;
        if (deg == d) { int p = atomicAdd(&cnt, 1); list[p] = i; }
    }
    float Wreg[Ff];
    { const float* Wd = W + (size_t)d * Ff * Ff;
      #pragma unroll
      for (int f = 0; f < Ff; f++) Wreg[f] = Wd[f * Ff + tid]; }
    const float breg = bias[d * Ff + tid];
    __syncthreads();
    const int n = cnt;
    const float* batch_atoms = atoms + (size_t)(a0 / Nn) * Nn * Ff;
    const int row0 = a0 % Nn;
    for (int ii = 0; ii < n; ii++) {
        const int i = list[ii];
        float s = batch_atoms[(row0 + i) * Ff + tid];
        #pragma unroll
        for (int j = 0; j < 6; j++) {
            int e = eds[i * 6 + j];
            if (e != -1) s += batch_atoms[e * Ff + tid];
        }
        float* buf = sv[ii & 1];
        buf[tid] = s;
        __syncthreads();
        float acc = breg;
        const float4* sv4 = (const float4*)buf;
        #pragma unroll
        for (int fc = 0; fc < Ff / 4; fc++) {
            float4 x = sv4[fc];
            acc = fmaf(x.x, Wreg[4 * fc + 0], acc);
            acc = fmaf(x.y, Wreg[4 * fc + 1], acc);
            acc = fmaf(x.z, Wreg[4 * fc + 2], acc);
            acc = fmaf(x.w, Wreg[4 * fc + 3], acc);
        }
        out[(size_t)(a0 + i) * Ff + tid] = fmaxf(acc, 0.0f);
    }
}

extern "C" void kernel_launch(void* const* d_in, const int* in_sizes, int n_in,
                              void* d_out, int out_size, void* d_ws, size_t ws_size,
                              hipStream_t stream) {
    const float* atoms = (const float*)d_in[0];
    const int*   edges = (const int*)d_in[1];
    const float* W     = (const float*)d_in[2];
    const float* bias  = (const float*)d_in[3];
    float*       outp  = (float*)d_out;

    if (ws_size >= WS_NEEDED) {
        ushort_t* Wt = (ushort_t*)d_ws;
        k0_wt<<<96, 1024, 0, stream>>>(W, Wt);
        k_fused<<<1024, 256, 0, stream>>>(atoms, edges, Wt, bias, outp);
    } else {
        graphconv_fallback<<<3072, 128, 0, stream>>>(atoms, edges, W, bias, outp);
    }
}

// Round 6
// 183.842 us; speedup vs baseline: 1.8245x; 1.8245x over previous
//
#include <hip/hip_runtime.h>

// GraphConv B=256,N=512,D=6,F=128,MAX_DEG=6.
// R11 post-mortem: concurrency theory CONFIRMED (3 indep blk/CU -> 3.0 TB/s,
// 2x of R10's 1.5) but quarter-blocks inflated L2-miss bytes 7.4x (4x atom
// re-stage across XCDs + out-write thrash) -> net 2x SLOWER. Law over 6 runs:
// dur = L2miss_bytes / BW(streams/CU). R12: keep R10's minimal 104 MB
// (full-molecule block) and fix the duty cycle at the source: phase-A
// __syncthreads() drains vmcnt(0) every slice (documented HIP-compiler
// behavior) -> memory pipe idles between 16KB slice bursts. Replace slice
// barriers with relaxed {s_waitcnt lgkmcnt(0); s_barrier} (LDS ordering
// kept, vmcnt NOT drained) + 4-deep prefetch ring (fully unrolled, static
// indices). Compiler emits counted vmcnt for pf reg-deps itself. Phase B
// unchanged (barrier-free). Bytes flat, duty up.

typedef short bf16x8 __attribute__((ext_vector_type(8)));
typedef float f32x4  __attribute__((ext_vector_type(4)));
typedef unsigned short ushort_t;
typedef unsigned int uint_t;

constexpr int Nn = 512;
constexpr int Ff = 128;

// ws: Wt bf16 [6][128][128] ([d][n][k])
constexpr size_t WS_NEEDED = 196608;

// Relaxed barrier: publish/consume LDS without draining the global-load
// queue (plain __syncthreads emits s_waitcnt vmcnt(0) first — the stall).
#define BAR_LDS() asm volatile("s_waitcnt lgkmcnt(0)\ns_barrier" ::: "memory")

__device__ inline ushort_t f2bf(float f) {              // round-to-nearest-even
    uint_t u = __float_as_uint(f);
    return (ushort_t)((u + 0x7FFFu + ((u >> 16) & 1u)) >> 16);
}

__device__ inline bool detect_is64(const int* edges32) {
    // int64 edges: odd dwords are sign-extension words in {0,-1}.
    int probe = edges32[2 * (threadIdx.x & 63) + 1];
    return __any(probe > 0) == 0;
}

// ---------------- k0: W fp32 [d][k][n] -> Wt bf16 [d][n][k] ----------------
__global__ __launch_bounds__(1024)
void k0_wt(const float* __restrict__ W, ushort_t* __restrict__ Wt) {
    int L = blockIdx.x * 1024 + threadIdx.x;     // 96 blocks x 1024 = 98304
    int d = L >> 14, rem = L & 16383;
    int n = rem >> 7, k = rem & 127;
    Wt[L] = f2bf(W[(d << 14) + (k << 7) + n]);   // W is 384KB -> L2-resident
}

// ---------------- fused: one molecule per block, 1024 threads ----------------
// Phase A: thread pair (2i,2i+1) owns gather row rlist[i], 4 floats each;
// 4-deep prefetch ring + relaxed barriers keep ~48KB/CU of loads in flight.
// Phase B: barrier-free flattened MFMA items, B-frags from global Wt.
__global__ __launch_bounds__(1024, 4)
void k_fused(const float* __restrict__ atoms,
             const int*   __restrict__ edges32,
             const ushort_t* __restrict__ Wt,
             const float* __restrict__ bias,
             float* __restrict__ out) {
    const int tid = threadIdx.x;
    const int mol = blockIdx.x;
    const bool is64 = detect_is64(edges32);      // convergent

    __shared__ ushort_t summed[Nn * 136];        // 139264 B (pad 136: 16B-aligned rows)
    __shared__ float4   abuf4[Nn * 2];           // 16384 B: one 8-float slice, swizzled
    __shared__ ushort_t rlist[Nn];               // 1024 B: row ids grouped by degree
    __shared__ int hist[6], base_sh[8];

    // --- prefetch ring: slices 0..3 (1 float4/thread/slice) ---
    const float4* gsrc = (const float4*)(atoms + (size_t)mol * (Nn * Ff));
    const int arow = tid >> 1, ac = tid & 1;     // staging coords
    float4 pf[4];
    #pragma unroll
    for (int k = 0; k < 4; k++) pf[k] = gsrc[arow * 32 + k * 2 + ac];

    // --- phase 0: degree ranks (threads < 512; 1 row each) ---
    if (tid < 6) hist[tid] = 0;
    __syncthreads();
    int deg = 0, rk = 0;
    if (tid < Nn) {
        const size_t eb = (size_t)mol * (Nn * 6) + (size_t)tid * 6;
        #pragma unroll
        for (int j = 0; j < 6; j++) {
            int e = is64 ? edges32[(eb + j) * 2] : edges32[eb + j];
            deg += (e >= 0) ? 1 : 0;
        }
        if (deg > 5) deg = 5;                    // input spec: deg<=5; guard OOB
        rk = atomicAdd(&hist[deg], 1);
    }
    __syncthreads();
    if (tid == 0) {
        int a = 0;
        #pragma unroll
        for (int d = 0; d < 6; d++) { base_sh[d] = a; a += hist[d]; }
    }
    __syncthreads();
    if (tid < Nn) rlist[base_sh[deg] + rk] = (ushort_t)tid;
    // publish slice 0 (consumes pf[0]); refill slot with slice 4.
    // Swizzle: granule c of row r at [2r + (c ^ (r&1))].
    abuf4[2 * arow + (ac ^ (arow & 1))] = pf[0];
    pf[0] = gsrc[arow * 32 + 4 * 2 + ac];
    BAR_LDS();                                   // rlist + abuf(slice0) ready

    // --- my gather row (rlist order -> degree-uniform waves) + its edges ---
    const int pr = tid >> 1, h = tid & 1;
    const int R = rlist[pr];
    int er[6];
    if (is64) {                                  // row edges = 48B, 16B-aligned
        const uint4* ep = (const uint4*)(edges32 + ((size_t)mol * (Nn * 6) + (size_t)R * 6) * 2);
        uint4 q0 = ep[0], q1 = ep[1], q2 = ep[2];
        er[0] = (int)q0.x; er[1] = (int)q0.z;
        er[2] = (int)q1.x; er[3] = (int)q1.z;
        er[4] = (int)q2.x; er[5] = (int)q2.z;
    } else {
        const int* ep = edges32 + (size_t)mol * (Nn * 6) + (size_t)R * 6;
        #pragma unroll
        for (int j = 0; j < 6; j++) er[j] = ep[j];
    }

    // --- phase A: 16 slices of 8 floats; fully unrolled (static pf ring) ---
    #pragma unroll
    for (int s = 0; s < 16; s++) {
        float4 a = abuf4[2 * R + (h ^ (R & 1))];               // self
        #pragma unroll
        for (int j = 0; j < 6; j++) {            // degree-uniform -> execz skip
            int e = er[j];
            if (e >= 0) {
                float4 v = abuf4[2 * e + (h ^ (e & 1))];
                a.x += v.x; a.y += v.y; a.z += v.z; a.w += v.w;
            }
        }
        uint2 o;
        o.x = (uint_t)f2bf(a.x) | ((uint_t)f2bf(a.y) << 16);
        o.y = (uint_t)f2bf(a.z) | ((uint_t)f2bf(a.w) << 16);
        *(uint2*)&summed[R * 136 + s * 8 + h * 4] = o;
        if (s < 15) {
            BAR_LDS();                           // all abuf reads of slice s done
            // publish slice s+1 (compiler inserts counted vmcnt for pf dep)
            abuf4[2 * arow + (ac ^ (arow & 1))] = pf[(s + 1) & 3];
            if (s + 5 < 16)                      // refill ring with slice s+5
                pf[(s + 1) & 3] = gsrc[arow * 32 + (s + 5) * 2 + ac];
            BAR_LDS();                           // abuf(s+1) ready
        }
    }
    BAR_LDS();                                   // summed complete for phase B

    // --- phase B: flattened barrier-free MFMA items, B-frags from global ---
    const int lane = tid & 63, wid = tid >> 6;   // wid 0..15
    const int kq = lane >> 4, ml = lane & 15;

    int cnts[6], cbase[6], Tp[7];
    {
        int a = 0, b = 0;
        #pragma unroll
        for (int d = 0; d < 6; d++) {
            cnts[d] = hist[d];
            cbase[d] = b; b += cnts[d];
            Tp[d] = a; a += ((cnts[d] + 15) >> 4) * 4;   // items = Td * 4 col-pairs
        }
        Tp[6] = a;
    }
    const int items = Tp[6];

    for (int it = wid; it < items; it += 16) {
        int d = 0;
        #pragma unroll
        for (int dd = 1; dd < 6; dd++) if (it >= Tp[dd]) d = dd;
        const int loc = it - Tp[d];
        const int ti = loc >> 2, ci = loc & 3;   // row-tile, col-pair
        const int cn = cnts[d], cb = cbase[d];

        int lidx = ti * 16 + ml;
        int cl = (lidx < cn) ? lidx : cn - 1;    // clamp; stores masked
        int row = rlist[cb + cl];
        bf16x8 af[4];                            // A: m=ml, k=kq*8+k0*32
        #pragma unroll
        for (int k0 = 0; k0 < 4; k0++)
            af[k0] = *(const bf16x8*)&summed[row * 136 + kq * 8 + k0 * 32];
        int orw[4];                              // C/D rows: kq*4+reg
        #pragma unroll
        for (int r = 0; r < 4; r++) {
            int li = ti * 16 + kq * 4 + r;
            orw[r] = (li < cn) ? (int)rlist[cb + li] : -1;
        }
        const ushort_t* wg = Wt + (size_t)d * 16384;
        #pragma unroll
        for (int n2 = 0; n2 < 2; n2++) {
            const int nt = ci * 2 + n2;
            bf16x8 bfr[4];                       // B: n=ml, k=kq*8+k0*32 (global, L2-hot)
            #pragma unroll
            for (int k0 = 0; k0 < 4; k0++)
                bfr[k0] = *(const bf16x8*)&wg[(nt * 16 + ml) * 128 + k0 * 32 + kq * 8];
            f32x4 c = {0.f, 0.f, 0.f, 0.f};
            #pragma unroll
            for (int k0 = 0; k0 < 4; k0++)
                c = __builtin_amdgcn_mfma_f32_16x16x32_bf16(af[k0], bfr[k0], c, 0, 0, 0);
            const int col = nt * 16 + ml;
            const float bc = bias[d * Ff + col];
            #pragma unroll
            for (int r = 0; r < 4; r++) {
                if (orw[r] >= 0) {
                    float v = c[r] + bc;
                    out[((size_t)mol * Nn + orw[r]) * Ff + col] = v > 0.f ? v : 0.f;
                }
            }
        }
    }
}

// ---------------- fallback (round-1 kernel) if ws too small ----------------
__global__ __launch_bounds__(128, 2)
void graphconv_fallback(const float* __restrict__ atoms,
                        const int* __restrict__ edges_raw,
                        const float* __restrict__ W,
                        const float* __restrict__ bias,
                        float* __restrict__ out) {
    const int tid = threadIdx.x;
    const int d = blockIdx.x % 6;
    const int k = blockIdx.x / 6;
    const int a0 = k * 256;
    __shared__ int eds[256 * 6];
    __shared__ int list[256];
    __shared__ int cnt;
    __shared__ float sv[2][Ff];
    bool is64;
    { int v = edges_raw[2 * (tid & 63) + 1]; is64 = (__ballot(v > 0) == 0ull); }
    if (!is64) { for (int i = tid; i < 256 * 6; i += 128) eds[i] = edges_raw[a0 * 6 + i]; }
    else       { for (int i = tid; i < 256 * 6; i += 128) eds[i] = edges_raw[2 * (a0 * 6 + i)]; }
    if (tid == 0) cnt = 0;
    __syncthreads();
    for (int i = tid; i < 256; i += 128) {
        int deg = 0;
        #pragma unroll
        for (int j = 0; j < 6; j++) deg += (eds[i * 6 + j] != -1) ? 1 : 0;
        if (deg == d) { int p = atomicAdd(&cnt, 1); list[p] = i; }
    }
    float Wreg[Ff];
    { const float* Wd = W + (size_t)d * Ff * Ff;
      #pragma unroll
      for (int f = 0; f < Ff; f++) Wreg[f] = Wd[f * Ff + tid]; }
    const float breg = bias[d * Ff + tid];
    __syncthreads();
    const int n = cnt;
    const float* batch_atoms = atoms + (size_t)(a0 / Nn) * Nn * Ff;
    const int row0 = a0 % Nn;
    for (int ii = 0; ii < n; ii++) {
        const int i = list[ii];
        float s = batch_atoms[(row0 + i) * Ff + tid];
        #pragma unroll
        for (int j = 0; j < 6; j++) {
            int e = eds[i * 6 + j];
            if (e != -1) s += batch_atoms[e * Ff + tid];
        }
        float* buf = sv[ii & 1];
        buf[tid] = s;
        __syncthreads();
        float acc = breg;
        const float4* sv4 = (const float4*)buf;
        #pragma unroll
        for (int fc = 0; fc < Ff / 4; fc++) {
            float4 x = sv4[fc];
            acc = fmaf(x.x, Wreg[4 * fc + 0], acc);
            acc = fmaf(x.y, Wreg[4 * fc + 1], acc);
            acc = fmaf(x.z, Wreg[4 * fc + 2], acc);
            acc = fmaf(x.w, Wreg[4 * fc + 3], acc);
        }
        out[(size_t)(a0 + i) * Ff + tid] = fmaxf(acc, 0.0f);
    }
}

extern "C" void kernel_launch(void* const* d_in, const int* in_sizes, int n_in,
                              void* d_out, int out_size, void* d_ws, size_t ws_size,
                              hipStream_t stream) {
    const float* atoms = (const float*)d_in[0];
    const int*   edges = (const int*)d_in[1];
    const float* W     = (const float*)d_in[2];
    const float* bias  = (const float*)d_in[3];
    float*       outp  = (float*)d_out;

    if (ws_size >= WS_NEEDED) {
        ushort_t* Wt = (ushort_t*)d_ws;
        k0_wt<<<96, 1024, 0, stream>>>(W, Wt);
        k_fused<<<256, 1024, 0, stream>>>(atoms, edges, Wt, bias, outp);
    } else {
        graphconv_fallback<<<3072, 128, 0, stream>>>(atoms, edges, W, bias, outp);
    }
}

// Round 7
// 155.171 us; speedup vs baseline: 2.1616x; 1.1848x over previous
//
#include <hip/hip_runtime.h>

// GraphConv B=256,N=512,D=6,F=128,MAX_DEG=6.
// R12 post-mortem: relaxed barriers raised BW 1.5->2.4 TB/s as predicted, but
// bytes rose 104->222 MB: pf[(s+1)&3] under #pragma-unroll+asm stayed
// runtime-indexed -> ext_vector ring spilled to SCRATCH (rule #20; VGPR stuck
// at 52 = the tell; +116MB = spill traffic). R13: same relaxed-barrier phase A
// but prefetch ring = TWO NAMED regs (pfA/pfB), manually 2x-unrolled body, all
// refs static -> no scratch. k0_wt coalesced via LDS transpose (was 128-stride
// scalar reads). Phase B + byte-minimal full-molecule structure = R10 exactly.

typedef short bf16x8 __attribute__((ext_vector_type(8)));
typedef float f32x4  __attribute__((ext_vector_type(4)));
typedef unsigned short ushort_t;
typedef unsigned int uint_t;

constexpr int Nn = 512;
constexpr int Ff = 128;

// ws: Wt bf16 [6][128][128] ([d][n][k])
constexpr size_t WS_NEEDED = 196608;

// Relaxed barrier: publish/consume LDS without draining the global-load
// queue (plain __syncthreads emits s_waitcnt vmcnt(0) first — the stall).
#define BAR_LDS() asm volatile("s_waitcnt lgkmcnt(0)\ns_barrier" ::: "memory")

__device__ inline ushort_t f2bf(float f) {              // round-to-nearest-even
    uint_t u = __float_as_uint(f);
    return (ushort_t)((u + 0x7FFFu + ((u >> 16) & 1u)) >> 16);
}

__device__ inline bool detect_is64(const int* edges32) {
    // int64 edges: odd dwords are sign-extension words in {0,-1}.
    int probe = edges32[2 * (threadIdx.x & 63) + 1];
    return __any(probe > 0) == 0;
}

// ---------------- k0: W fp32 [d][k][n] -> Wt bf16 [d][n][k] ----------------
// Coalesced both sides via LDS transpose (pad 133: gcd(133,32)=1, conflict-free).
__global__ __launch_bounds__(1024)
void k0_wt(const float* __restrict__ W, ushort_t* __restrict__ Wt) {
    __shared__ float w[128 * 133];               // 68096 B
    const int d = blockIdx.x;
    const float* src = W + (size_t)d * 16384;
    #pragma unroll
    for (int i = 0; i < 16; i++) {
        int idx = threadIdx.x + i * 1024;        // [k][n] linear, coalesced read
        w[(idx >> 7) * 133 + (idx & 127)] = src[idx];
    }
    __syncthreads();
    ushort_t* dst = Wt + (size_t)d * 16384;
    #pragma unroll
    for (int i = 0; i < 16; i++) {
        int idx = threadIdx.x + i * 1024;        // [n][k] linear, coalesced write
        dst[idx] = f2bf(w[(idx & 127) * 133 + (idx >> 7)]);
    }
}

// ---------------- fused: one molecule per block, 1024 threads ----------------
// Phase A: thread pair (2i,2i+1) owns gather row rlist[i], 4 floats each;
// 2-deep NAMED prefetch (pfA/pfB) + relaxed barriers: loads issued ~2 periods
// ahead, never drained by a barrier. Phase B: barrier-free flattened MFMA
// items, B-frags direct from global Wt (L2-hot).
__global__ __launch_bounds__(1024, 4)
void k_fused(const float* __restrict__ atoms,
             const int*   __restrict__ edges32,
             const ushort_t* __restrict__ Wt,
             const float* __restrict__ bias,
             float* __restrict__ out) {
    const int tid = threadIdx.x;
    const int mol = blockIdx.x;
    const bool is64 = detect_is64(edges32);      // convergent

    __shared__ ushort_t summed[Nn * 136];        // 139264 B (pad 136: 16B-aligned rows)
    __shared__ float4   abuf4[Nn * 2];           // 16384 B: one 8-float slice, swizzled
    __shared__ ushort_t rlist[Nn];               // 1024 B: row ids grouped by degree
    __shared__ int hist[6], base_sh[8];

    // --- prefetch slices 0,1 into NAMED regs (loads overlap phase 0) ---
    const float4* gsrc = (const float4*)(atoms + (size_t)mol * (Nn * Ff));
    const int arow = tid >> 1, ac = tid & 1;     // staging coords
    float4 pfA = gsrc[arow * 32 + 0 * 2 + ac];   // slice 0
    float4 pfB = gsrc[arow * 32 + 1 * 2 + ac];   // slice 1

    // --- phase 0: degree ranks (threads < 512; 1 row each) ---
    if (tid < 6) hist[tid] = 0;
    __syncthreads();
    int deg = 0, rk = 0;
    if (tid < Nn) {
        const size_t eb = (size_t)mol * (Nn * 6) + (size_t)tid * 6;
        #pragma unroll
        for (int j = 0; j < 6; j++) {
            int e = is64 ? edges32[(eb + j) * 2] : edges32[eb + j];
            deg += (e >= 0) ? 1 : 0;
        }
        if (deg > 5) deg = 5;                    // input spec: deg<=5; guard OOB
        rk = atomicAdd(&hist[deg], 1);
    }
    __syncthreads();
    if (tid == 0) {
        int a = 0;
        #pragma unroll
        for (int d = 0; d < 6; d++) { base_sh[d] = a; a += hist[d]; }
    }
    __syncthreads();
    if (tid < Nn) rlist[base_sh[deg] + rk] = (ushort_t)tid;
    // publish slice 0 (consumes pfA); refill pfA with slice 2.
    // Swizzle: granule c of row r at [2r + (c ^ (r&1))].
    abuf4[2 * arow + (ac ^ (arow & 1))] = pfA;
    pfA = gsrc[arow * 32 + 2 * 2 + ac];
    BAR_LDS();                                   // rlist + abuf(slice0) ready

    // --- my gather row (rlist order -> degree-uniform waves) + its edges ---
    const int pr = tid >> 1, h = tid & 1;
    const int R = rlist[pr];
    int er[6];
    if (is64) {                                  // row edges = 48B, 16B-aligned
        const uint4* ep = (const uint4*)(edges32 + ((size_t)mol * (Nn * 6) + (size_t)R * 6) * 2);
        uint4 q0 = ep[0], q1 = ep[1], q2 = ep[2];
        er[0] = (int)q0.x; er[1] = (int)q0.z;
        er[2] = (int)q1.x; er[3] = (int)q1.z;
        er[4] = (int)q2.x; er[5] = (int)q2.z;
    } else {
        const int* ep = edges32 + (size_t)mol * (Nn * 6) + (size_t)R * 6;
        #pragma unroll
        for (int j = 0; j < 6; j++) er[j] = ep[j];
    }
    const int selfb = 2 * R + (h ^ (R & 1));     // own abuf base (invariant)
    const int pubb  = 2 * arow + (ac ^ (arow & 1));

    // --- phase A: 16 slices; runtime loop i=0..7, 2 slices/iter, static regs ---
    for (int i = 0; i < 8; i++) {
        const int s0 = 2 * i;
        // ---- gather slice s0 (even) ----
        {
            float4 a = abuf4[selfb];
            #pragma unroll
            for (int j = 0; j < 6; j++) {        // degree-uniform -> execz skip
                int e = er[j];
                if (e >= 0) {
                    float4 v = abuf4[2 * e + (h ^ (e & 1))];
                    a.x += v.x; a.y += v.y; a.z += v.z; a.w += v.w;
                }
            }
            uint2 o;
            o.x = (uint_t)f2bf(a.x) | ((uint_t)f2bf(a.y) << 16);
            o.y = (uint_t)f2bf(a.z) | ((uint_t)f2bf(a.w) << 16);
            *(uint2*)&summed[R * 136 + s0 * 8 + h * 4] = o;
        }
        BAR_LDS();                               // abuf(s0) reads done
        abuf4[pubb] = pfB;                       // publish slice 2i+1 (counted vmcnt)
        if (i < 7) pfB = gsrc[arow * 32 + (2 * i + 3) * 2 + ac];
        BAR_LDS();                               // abuf(2i+1) ready
        // ---- gather slice s0+1 (odd) ----
        {
            float4 a = abuf4[selfb];
            #pragma unroll
            for (int j = 0; j < 6; j++) {
                int e = er[j];
                if (e >= 0) {
                    float4 v = abuf4[2 * e + (h ^ (e & 1))];
                    a.x += v.x; a.y += v.y; a.z += v.z; a.w += v.w;
                }
            }
            uint2 o;
            o.x = (uint_t)f2bf(a.x) | ((uint_t)f2bf(a.y) << 16);
            o.y = (uint_t)f2bf(a.z) | ((uint_t)f2bf(a.w) << 16);
            *(uint2*)&summed[R * 136 + (s0 + 1) * 8 + h * 4] = o;
        }
        if (i < 7) {
            BAR_LDS();                           // abuf(2i+1) reads done
            abuf4[pubb] = pfA;                   // publish slice 2i+2
            if (i < 6) pfA = gsrc[arow * 32 + (2 * i + 4) * 2 + ac];
            BAR_LDS();                           // abuf(2i+2) ready
        }
    }
    BAR_LDS();                                   // summed complete for phase B

    // --- phase B: flattened barrier-free MFMA items, B-frags from global ---
    const int lane = tid & 63, wid = tid >> 6;   // wid 0..15
    const int kq = lane >> 4, ml = lane & 15;

    int cnts[6], cbase[6], Tp[7];
    {
        int a = 0, b = 0;
        #pragma unroll
        for (int d = 0; d < 6; d++) {
            cnts[d] = hist[d];
            cbase[d] = b; b += cnts[d];
            Tp[d] = a; a += ((cnts[d] + 15) >> 4) * 4;   // items = Td * 4 col-pairs
        }
        Tp[6] = a;
    }
    const int items = Tp[6];

    for (int it = wid; it < items; it += 16) {
        int d = 0;
        #pragma unroll
        for (int dd = 1; dd < 6; dd++) if (it >= Tp[dd]) d = dd;
        const int loc = it - Tp[d];
        const int ti = loc >> 2, ci = loc & 3;   // row-tile, col-pair
        const int cn = cnts[d], cb = cbase[d];

        int lidx = ti * 16 + ml;
        int cl = (lidx < cn) ? lidx : cn - 1;    // clamp; stores masked
        int row = rlist[cb + cl];
        bf16x8 af[4];                            // A: m=ml, k=kq*8+k0*32
        #pragma unroll
        for (int k0 = 0; k0 < 4; k0++)
            af[k0] = *(const bf16x8*)&summed[row * 136 + kq * 8 + k0 * 32];
        int orw[4];                              // C/D rows: kq*4+reg
        #pragma unroll
        for (int r = 0; r < 4; r++) {
            int li = ti * 16 + kq * 4 + r;
            orw[r] = (li < cn) ? (int)rlist[cb + li] : -1;
        }
        const ushort_t* wg = Wt + (size_t)d * 16384;
        #pragma unroll
        for (int n2 = 0; n2 < 2; n2++) {
            const int nt = ci * 2 + n2;
            bf16x8 bfr[4];                       // B: n=ml, k=kq*8+k0*32 (global, L2-hot)
            #pragma unroll
            for (int k0 = 0; k0 < 4; k0++)
                bfr[k0] = *(const bf16x8*)&wg[(nt * 16 + ml) * 128 + k0 * 32 + kq * 8];
            f32x4 c = {0.f, 0.f, 0.f, 0.f};
            #pragma unroll
            for (int k0 = 0; k0 < 4; k0++)
                c = __builtin_amdgcn_mfma_f32_16x16x32_bf16(af[k0], bfr[k0], c, 0, 0, 0);
            const int col = nt * 16 + ml;
            const float bc = bias[d * Ff + col];
            #pragma unroll
            for (int r = 0; r < 4; r++) {
                if (orw[r] >= 0) {
                    float v = c[r] + bc;
                    out[((size_t)mol * Nn + orw[r]) * Ff + col] = v > 0.f ? v : 0.f;
                }
            }
        }
    }
}

// ---------------- fallback (round-1 kernel) if ws too small ----------------
__global__ __launch_bounds__(128, 2)
void graphconv_fallback(const float* __restrict__ atoms,
                        const int* __restrict__ edges_raw,
                        const float* __restrict__ W,
                        const float* __restrict__ bias,
                        float* __restrict__ out) {
    const int tid = threadIdx.x;
    const int d = blockIdx.x % 6;
    const int k = blockIdx.x / 6;
    const int a0 = k * 256;
    __shared__ int eds[256 * 6];
    __shared__ int list[256];
    __shared__ int cnt;
    __shared__ float sv[2][Ff];
    bool is64;
    { int v = edges_raw[2 * (tid & 63) + 1]; is64 = (__ballot(v > 0) == 0ull); }
    if (!is64) { for (int i = tid; i < 256 * 6; i += 128) eds[i] = edges_raw[a0 * 6 + i]; }
    else       { for (int i = tid; i < 256 * 6; i += 128) eds[i] = edges_raw[2 * (a0 * 6 + i)]; }
    if (tid == 0) cnt = 0;
    __syncthreads();
    for (int i = tid; i < 256; i += 128) {
        int deg = 0;
        #pragma unroll
        for (int j = 0; j < 6; j++) deg += (eds[i * 6 + j] != -1) ? 1 : 0;
        if (deg == d) { int p = atomicAdd(&cnt, 1); list[p] = i; }
    }
    float Wreg[Ff];
    { const float* Wd = W + (size_t)d * Ff * Ff;
      #pragma unroll
      for (int f = 0; f < Ff; f++) Wreg[f] = Wd[f * Ff + tid]; }
    const float breg = bias[d * Ff + tid];
    __syncthreads();
    const int n = cnt;
    const float* batch_atoms = atoms + (size_t)(a0 / Nn) * Nn * Ff;
    const int row0 = a0 % Nn;
    for (int ii = 0; ii < n; ii++) {
        const int i = list[ii];
        float s = batch_atoms[(row0 + i) * Ff + tid];
        #pragma unroll
        for (int j = 0; j < 6; j++) {
            int e = eds[i * 6 + j];
            if (e != -1) s += batch_atoms[e * Ff + tid];
        }
        float* buf = sv[ii & 1];
        buf[tid] = s;
        __syncthreads();
        float acc = breg;
        const float4* sv4 = (const float4*)buf;
        #pragma unroll
        for (int fc = 0; fc < Ff / 4; fc++) {
            float4 x = sv4[fc];
            acc = fmaf(x.x, Wreg[4 * fc + 0], acc);
            acc = fmaf(x.y, Wreg[4 * fc + 1], acc);
            acc = fmaf(x.z, Wreg[4 * fc + 2], acc);
            acc = fmaf(x.w, Wreg[4 * fc + 3], acc);
        }
        out[(size_t)(a0 + i) * Ff + tid] = fmaxf(acc, 0.0f);
    }
}

extern "C" void kernel_launch(void* const* d_in, const int* in_sizes, int n_in,
                              void* d_out, int out_size, void* d_ws, size_t ws_size,
                              hipStream_t stream) {
    const float* atoms = (const float*)d_in[0];
    const int*   edges = (const int*)d_in[1];
    const float* W     = (const float*)d_in[2];
    const float* bias  = (const float*)d_in[3];
    float*       outp  = (float*)d_out;

    if (ws_size >= WS_NEEDED) {
        ushort_t* Wt = (ushort_t*)d_ws;
        k0_wt<<<6, 1024, 0, stream>>>(W, Wt);
        k_fused<<<256, 1024, 0, stream>>>(atoms, edges, Wt, bias, outp);
    } else {
        graphconv_fallback<<<3072, 128, 0, stream>>>(atoms, edges, W, bias, outp);
    }
}